// Round 11
// baseline (305.291 us; speedup 1.0000x reference)
//
#include <hip/hip_runtime.h>
#include <stdint.h>

typedef __bf16 bf16;
typedef bf16 bf16x8 __attribute__((ext_vector_type(8)));
typedef float f32x4 __attribute__((ext_vector_type(4)));
typedef float f32x16 __attribute__((ext_vector_type(16)));
typedef uint32_t u32x4 __attribute__((ext_vector_type(4)));

static __device__ __forceinline__ void async_cp16(const bf16* gsrc, bf16* ldst) {
  __builtin_amdgcn_global_load_lds(
      (const __attribute__((address_space(1))) uint32_t*)gsrc,
      (__attribute__((address_space(3))) uint32_t*)ldst, 16, 0, 0);
}

static __device__ __forceinline__ f32x16 mfma32(bf16x8 a, bf16x8 b, f32x16 c) {
  return __builtin_amdgcn_mfma_f32_32x32x16_bf16(a, b, c, 0, 0, 0);
}
static __device__ __forceinline__ f32x4 mfma16(bf16x8 a, bf16x8 b, f32x4 c) {
  return __builtin_amdgcn_mfma_f32_16x16x32_bf16(a, b, c, 0, 0, 0);
}

static __device__ __forceinline__ uint32_t cvtpk(float lo, float hi) {
  uint32_t r;
  asm("v_cvt_pk_bf16_f32 %0, %1, %2" : "=v"(r) : "v"(lo), "v"(hi));
  return r;
}
static __device__ __forceinline__ void plswap(uint32_t& a, uint32_t& b) {
  asm("v_permlane32_swap_b32 %0, %1" : "+v"(a), "+v"(b));
}

// ---------------- fp32 -> bf16 conversion (all tensors, one launch) ----------------
__global__ __launch_bounds__(256) void convert_all(
    const float* __restrict__ x, const float* __restrict__ ctx,
    const float* __restrict__ wq, const float* __restrict__ wk,
    const float* __restrict__ wv, const float* __restrict__ wo,
    bf16* __restrict__ xb, bf16* __restrict__ cb,
    bf16* __restrict__ wqb, bf16* __restrict__ wkb,
    bf16* __restrict__ wvb, bf16* __restrict__ wob) {
  int id = blockIdx.x;
  const float* s; bf16* d; int base;
  if (id < 8192)        { s = x;   d = xb;  base = id; }
  else if (id < 24576)  { s = ctx; d = cb;  base = id - 8192; }
  else if (id < 25600)  { s = wq;  d = wqb; base = id - 24576; }
  else if (id < 26624)  { s = wk;  d = wkb; base = id - 25600; }
  else if (id < 27648)  { s = wv;  d = wvb; base = id - 26624; }
  else                  { s = wo;  d = wob; base = id - 27648; }
  int i = base * 256 + threadIdx.x;
  float4 v = ((const float4*)s)[i];
  ushort4 o;
  o.x = __builtin_bit_cast(unsigned short, (bf16)v.x);
  o.y = __builtin_bit_cast(unsigned short, (bf16)v.y);
  o.z = __builtin_bit_cast(unsigned short, (bf16)v.z);
  o.w = __builtin_bit_cast(unsigned short, (bf16)v.w);
  ((ushort4*)d)[i] = o;
}

// ---------------- 256x256 GEMM, 4-deep ring pipeline (counted vmcnt, never drains) ----
// BK=32, K=1024 fixed (NT=32). 8 waves (2Mx4N), per-wave C = 128x64.
// LDS: 4 ring slots x (A 16KB + B 16KB) = 128 KiB.
// Iter t: stage tile t+3 (slot (t+3)&3) -> compute tile t -> vmcnt(8) confirms t+1
// (8 younger loads from t+2,t+3 stay in flight) -> barrier. Peel last 3 tiles 8/4/0.
// Swizzle (64B rows): store src chunk = (l&3)^((l>>3)&3); read chunk = kg^((lr>>1)&3).
template <int OUT_F32, int BIAS_ROW, int ROPE>
__global__ __launch_bounds__(512, 2) void gemm256(
    const bf16* __restrict__ A, const bf16* __restrict__ Bw,
    const float* __restrict__ bias, void* __restrict__ Cout,
    int N, float oscale, const float* __restrict__ freqs) {
  __shared__ __align__(16) bf16 sA[4][8192];
  __shared__ __align__(16) bf16 sB[4][8192];
  const int K = 1024;

  int per = gridDim.x >> 3;
  int id = blockIdx.x;
  int swz = (id & 7) * per + (id >> 3);
  int NB = N >> 8;
  int mb = swz / NB, nb = swz % NB;

  int tid = threadIdx.x;
  int l = tid & 63, w = tid >> 6;
  int wm = w >> 2, wn = w & 3;
  int lr = l & 15, kg = l >> 4;

  // staging: instr covers 128 rows (8 waves x 16); lane -> (row rw, 16B chunk l&3)
  int rw = w * 16 + (l >> 2);
  int cs = ((l & 3) ^ ((l >> 3) & 3)) * 8;  // pre-swizzled source col (elems)
  const bf16* Ab = A + (size_t)(mb * 256 + rw) * K + cs;
  const bf16* Bb = Bw + (size_t)(nb * 256 + rw) * K + cs;

  auto stage = [&](int kt) {
    int buf = kt & 3;
    async_cp16(Ab + kt * 32, &sA[buf][w * 512]);
    async_cp16(Ab + kt * 32 + (size_t)128 * K, &sA[buf][w * 512 + 4096]);
    async_cp16(Bb + kt * 32, &sB[buf][w * 512]);
    async_cp16(Bb + kt * 32 + (size_t)128 * K, &sB[buf][w * 512 + 4096]);
  };

  f32x4 acc[8][4];
#pragma unroll
  for (int i = 0; i < 8; i++)
#pragma unroll
    for (int j = 0; j < 4; j++) acc[i][j] = f32x4{0.f, 0.f, 0.f, 0.f};

  int xr = (kg ^ ((lr >> 1) & 3)) * 8;  // swizzled k-chunk for reads (uniform per lane)

  auto compute = [&](int t) {
    const bf16* pA = sA[t & 3];
    const bf16* pB = sB[t & 3];
    bf16x8 af[8], bfv[4];
#pragma unroll
    for (int mf = 0; mf < 8; mf++) {
      int ar = wm * 128 + mf * 16 + lr;
      af[mf] = *(const bf16x8*)&pA[ar * 32 + xr];
    }
#pragma unroll
    for (int nf = 0; nf < 4; nf++) {
      int br = wn * 64 + nf * 16 + lr;
      bfv[nf] = *(const bf16x8*)&pB[br * 32 + xr];
    }
    __builtin_amdgcn_s_setprio(1);
#pragma unroll
    for (int mf = 0; mf < 8; mf++)
#pragma unroll
      for (int nf = 0; nf < 4; nf++)
        acc[mf][nf] = mfma16(af[mf], bfv[nf], acc[mf][nf]);
    __builtin_amdgcn_s_setprio(0);
  };

  // prologue: 3 tiles in flight, confirm tile 0 only (8 younger stay airborne)
  stage(0); stage(1); stage(2);
  asm volatile("s_waitcnt vmcnt(8)" ::: "memory");
  __builtin_amdgcn_s_barrier();
  __builtin_amdgcn_sched_barrier(0);

  for (int t = 0; t < 29; ++t) {
    stage(t + 3);                 // slot (t-1)&3: freed by end-of-(t-1) barrier
    compute(t);
    asm volatile("s_waitcnt vmcnt(8)" ::: "memory");  // confirms t+1
    __builtin_amdgcn_s_barrier();
    __builtin_amdgcn_sched_barrier(0);
  }
  compute(29);
  asm volatile("s_waitcnt vmcnt(4)" ::: "memory");    // confirms 30
  __builtin_amdgcn_s_barrier();
  __builtin_amdgcn_sched_barrier(0);
  compute(30);
  asm volatile("s_waitcnt vmcnt(0)" ::: "memory");    // confirms 31
  __builtin_amdgcn_s_barrier();
  __builtin_amdgcn_sched_barrier(0);
  compute(31);

  // ---- epilogue ----
  int row0 = mb * 256 + wm * 128 + (l >> 4) * 4;
  int col0 = nb * 256 + wn * 64 + lr;
  float sgn = (lr & 1) ? 1.f : -1.f;
#pragma unroll
  for (int fc = 0; fc < 4; fc++) {
    int c = col0 + fc * 16;
    float bi = BIAS_ROW ? 0.f : bias[c];
#pragma unroll
    for (int fr = 0; fr < 8; fr++) {
#pragma unroll
      for (int j = 0; j < 4; j++) {
        int r = row0 + fr * 16 + j;
        float v = acc[fr][fc][j] + (BIAS_ROW ? bias[r] : bi);
        if (ROPE) {
          float pv = __shfl_xor(v, 1, 64);
          float2 f = ((const float2*)freqs)[(size_t)(r & 2047) * 32 + ((c & 63) >> 1)];
          v = v * f.x + sgn * pv * f.y;
        }
        v *= oscale;
        if (OUT_F32)
          ((float*)Cout)[(size_t)r * N + c] = v;
        else
          ((bf16*)Cout)[(size_t)r * N + c] = (bf16)v;
      }
    }
  }
}

// ---------------- flash attention: swapped-QK^T 32x32, fixed-max softmax ----------------
__global__ __launch_bounds__(256, 4) void attn_fwd(
    const bf16* __restrict__ Q, const bf16* __restrict__ Kb,
    const bf16* __restrict__ VT, bf16* __restrict__ O) {
  __shared__ __align__(16) bf16 sK[2][4096];
  __shared__ __align__(16) bf16 sV[2][4096];

  int nblk = blockIdx.x;
  int bh = (nblk & 7) * 16 + (nblk >> 6);
  int qt = (nblk >> 3) & 7;
  int b = bh >> 4, h = bh & 15;

  int t = threadIdx.x, l = t & 63, w = t >> 6;
  int ln = l & 31, hi = l >> 5;

  int qg = qt * 128 + w * 32 + ln;
  const bf16* qp = Q + ((size_t)(b * 1024 + qg) * 16 + h) * 64 + hi * 8;
  bf16x8 qf[4];
#pragma unroll
  for (int ds = 0; ds < 4; ds++) qf[ds] = *(const bf16x8*)(qp + ds * 16);

  const bf16* kbase = Kb + ((size_t)b * 2048 * 16 + h) * 64;
  const bf16* vtbase = VT + (size_t)(h * 64) * 16384 + b * 2048;

  int krow = w * 8 + (l >> 3);
  int cg1 = ((l & 7) ^ (krow & 7) ^ ((krow >> 3) & 7)) * 8;
  int r2 = krow + 32;
  int cg2 = ((l & 7) ^ (r2 & 7) ^ ((r2 >> 3) & 7)) * 8;

  auto stageK = [&](int kv0, int nb) {
    async_cp16(kbase + (size_t)(kv0 + krow) * 1024 + cg1, &sK[nb][w * 512]);
    async_cp16(kbase + (size_t)(kv0 + r2) * 1024 + cg2, &sK[nb][2048 + w * 512]);
  };
  auto stageV = [&](int kv0, int nb) {
    async_cp16(vtbase + (size_t)krow * 16384 + kv0 + cg1, &sV[nb][w * 512]);
    async_cp16(vtbase + (size_t)r2 * 16384 + kv0 + cg2, &sV[nb][2048 + w * 512]);
  };

  f32x16 o0, o1, s0, s1, lacc, zero16;
#pragma unroll
  for (int i = 0; i < 16; i++) {
    o0[i] = 0.f; o1[i] = 0.f; lacc[i] = 0.f; zero16[i] = 0.f;
  }
  uint32_t one2 = 0x3f803f80u;
  u32x4 onesw; onesw[0] = one2; onesw[1] = one2; onesw[2] = one2; onesw[3] = one2;
  bf16x8 onesf = __builtin_bit_cast(bf16x8, onesw);

  stageK(0, 0);
  stageV(0, 0);
  __syncthreads();
  int cur = 0;

  int x0 = ((ln & 7) ^ (ln >> 3)) << 3;
  int x1 = x0 ^ (4 << 3);

  for (int tt = 0; tt < 32; tt++) {
    if (tt < 31) { stageK(tt * 64 + 64, cur ^ 1); stageV(tt * 64 + 64, cur ^ 1); }

    __builtin_amdgcn_s_setprio(1);
    {
      int boff = hi * 8;
      bf16x8 kf0 = *(const bf16x8*)&sK[cur][ln * 64 + (boff ^ x0)];
      bf16x8 kf1 = *(const bf16x8*)&sK[cur][(ln + 32) * 64 + (boff ^ x1)];
      s0 = mfma32(kf0, qf[0], zero16);
      s1 = mfma32(kf1, qf[0], zero16);
    }
#pragma unroll
    for (int ds = 1; ds < 4; ds++) {
      int boff = ds * 16 + hi * 8;
      bf16x8 kf0 = *(const bf16x8*)&sK[cur][ln * 64 + (boff ^ x0)];
      bf16x8 kf1 = *(const bf16x8*)&sK[cur][(ln + 32) * 64 + (boff ^ x1)];
      s0 = mfma32(kf0, qf[ds], s0);
      s1 = mfma32(kf1, qf[ds], s1);
    }
    __builtin_amdgcn_s_setprio(0);

#pragma unroll
    for (int i = 0; i < 16; i++) {
      s0[i] = __builtin_amdgcn_exp2f(s0[i]);
      s1[i] = __builtin_amdgcn_exp2f(s1[i]);
    }

    bf16x8 pa[4];
    auto mkfrags = [&](const f32x16& sv, int base) {
#pragma unroll
      for (int u = 0; u < 2; u++) {
        uint32_t w0a = cvtpk(sv[8 * u + 0], sv[8 * u + 1]);
        uint32_t w0b = cvtpk(sv[8 * u + 4], sv[8 * u + 5]);
        plswap(w0a, w0b);
        uint32_t w1a = cvtpk(sv[8 * u + 2], sv[8 * u + 3]);
        uint32_t w1b = cvtpk(sv[8 * u + 6], sv[8 * u + 7]);
        plswap(w1a, w1b);
        u32x4 tmp;
        tmp[0] = w0a; tmp[1] = w1a; tmp[2] = w0b; tmp[3] = w1b;
        pa[base + u] = __builtin_bit_cast(bf16x8, tmp);
      }
    };
    mkfrags(s0, 0);
    mkfrags(s1, 2);

    __builtin_amdgcn_s_setprio(1);
#pragma unroll
    for (int ks = 0; ks < 4; ks++) {
      int koff = ks * 16 + hi * 8;
      bf16x8 vf0 = *(const bf16x8*)&sV[cur][ln * 64 + (koff ^ x0)];
      bf16x8 vf1 = *(const bf16x8*)&sV[cur][(ln + 32) * 64 + (koff ^ x1)];
      o0 = mfma32(vf0, pa[ks], o0);
      o1 = mfma32(vf1, pa[ks], o1);
      lacc = mfma32(onesf, pa[ks], lacc);
    }
    __builtin_amdgcn_s_setprio(0);

    __syncthreads();
    cur ^= 1;
  }

  float inv = __builtin_amdgcn_rcpf(lacc[0]);
  bf16* obase = O + ((size_t)(b * 1024 + qt * 128 + w * 32 + ln) * 16 + h) * 64;
#pragma unroll
  for (int g = 0; g < 4; g++) {
    ushort4 p0, p1;
    p0.x = __builtin_bit_cast(unsigned short, (bf16)(o0[4 * g + 0] * inv));
    p0.y = __builtin_bit_cast(unsigned short, (bf16)(o0[4 * g + 1] * inv));
    p0.z = __builtin_bit_cast(unsigned short, (bf16)(o0[4 * g + 2] * inv));
    p0.w = __builtin_bit_cast(unsigned short, (bf16)(o0[4 * g + 3] * inv));
    p1.x = __builtin_bit_cast(unsigned short, (bf16)(o1[4 * g + 0] * inv));
    p1.y = __builtin_bit_cast(unsigned short, (bf16)(o1[4 * g + 1] * inv));
    p1.z = __builtin_bit_cast(unsigned short, (bf16)(o1[4 * g + 2] * inv));
    p1.w = __builtin_bit_cast(unsigned short, (bf16)(o1[4 * g + 3] * inv));
    *(ushort4*)&obase[8 * g + 4 * hi] = p0;
    *(ushort4*)&obase[32 + 8 * g + 4 * hi] = p1;
  }
}

// ---------------- launcher ----------------
extern "C" void kernel_launch(void* const* d_in, const int* in_sizes, int n_in,
                              void* d_out, int out_size, void* d_ws, size_t ws_size,
                              hipStream_t stream) {
  const float* x     = (const float*)d_in[0];
  const float* ctx   = (const float*)d_in[1];
  const float* freqs = (const float*)d_in[2];
  const float* wq    = (const float*)d_in[3];
  const float* bq    = (const float*)d_in[4];
  const float* wk    = (const float*)d_in[5];
  const float* bk    = (const float*)d_in[6];
  const float* wv    = (const float*)d_in[7];
  const float* bv    = (const float*)d_in[8];
  const float* wo    = (const float*)d_in[9];
  const float* bo    = (const float*)d_in[10];

  char* p = (char*)d_ws;
  bf16* xb  = (bf16*)p; p += (size_t)8192 * 1024 * 2;
  bf16* cb  = (bf16*)p; p += (size_t)16384 * 1024 * 2;
  bf16* wqb = (bf16*)p; p += (size_t)1024 * 1024 * 2;
  bf16* wkb = (bf16*)p; p += (size_t)1024 * 1024 * 2;
  bf16* wvb = (bf16*)p; p += (size_t)1024 * 1024 * 2;
  bf16* wob = (bf16*)p; p += (size_t)1024 * 1024 * 2;
  bf16* qb  = (bf16*)p; p += (size_t)8192 * 1024 * 2;
  bf16* kb  = (bf16*)p; p += (size_t)16384 * 1024 * 2;
  bf16* vt  = (bf16*)p; p += (size_t)16384 * 1024 * 2;  // V^T [1024][16384]
  bf16* ob  = xb;  // alias: x consumed before attention output is written

  const float K2 = 0.18033688011112042f;  // (1/sqrt(64)) * log2(e)

  convert_all<<<28672, 256, 0, stream>>>(x, ctx, wq, wk, wv, wo,
                                         xb, cb, wqb, wkb, wvb, wob);
  gemm256<0, 0, 0><<<128, 512, 0, stream>>>(xb, wqb, bq, qb, 1024, K2, nullptr);
  gemm256<0, 0, 1><<<256, 512, 0, stream>>>(cb, wkb, bk, kb, 1024, 1.0f, freqs);
  gemm256<0, 1, 0><<<256, 512, 0, stream>>>(wvb, cb, bv, vt, 16384, 1.0f, nullptr);
  attn_fwd<<<1024, 256, 0, stream>>>(qb, kb, vt, ob);
  gemm256<1, 0, 0><<<128, 512, 0, stream>>>(ob, wob, bo, d_out, 1024, 1.0f, nullptr);
}

// Round 12
// 300.428 us; speedup vs baseline: 1.0162x; 1.0162x over previous
//
#include <hip/hip_runtime.h>
#include <stdint.h>

typedef __bf16 bf16;
typedef bf16 bf16x8 __attribute__((ext_vector_type(8)));
typedef float f32x4 __attribute__((ext_vector_type(4)));
typedef float f32x16 __attribute__((ext_vector_type(16)));
typedef uint32_t u32x4 __attribute__((ext_vector_type(4)));

static __device__ __forceinline__ void async_cp16(const bf16* gsrc, bf16* ldst) {
  __builtin_amdgcn_global_load_lds(
      (const __attribute__((address_space(1))) uint32_t*)gsrc,
      (__attribute__((address_space(3))) uint32_t*)ldst, 16, 0, 0);
}

static __device__ __forceinline__ f32x16 mfma32(bf16x8 a, bf16x8 b, f32x16 c) {
  return __builtin_amdgcn_mfma_f32_32x32x16_bf16(a, b, c, 0, 0, 0);
}
static __device__ __forceinline__ f32x4 mfma16(bf16x8 a, bf16x8 b, f32x4 c) {
  return __builtin_amdgcn_mfma_f32_16x16x32_bf16(a, b, c, 0, 0, 0);
}

static __device__ __forceinline__ uint32_t cvtpk(float lo, float hi) {
  uint32_t r;
  asm("v_cvt_pk_bf16_f32 %0, %1, %2" : "=v"(r) : "v"(lo), "v"(hi));
  return r;
}
static __device__ __forceinline__ void plswap(uint32_t& a, uint32_t& b) {
  asm("v_permlane32_swap_b32 %0, %1" : "+v"(a), "+v"(b));
}

// ---------------- fp32 -> bf16 conversion (all tensors, one launch) ----------------
__global__ __launch_bounds__(256) void convert_all(
    const float* __restrict__ x, const float* __restrict__ ctx,
    const float* __restrict__ wq, const float* __restrict__ wk,
    const float* __restrict__ wv, const float* __restrict__ wo,
    bf16* __restrict__ xb, bf16* __restrict__ cb,
    bf16* __restrict__ wqb, bf16* __restrict__ wkb,
    bf16* __restrict__ wvb, bf16* __restrict__ wob) {
  int id = blockIdx.x;
  const float* s; bf16* d; int base;
  if (id < 8192)        { s = x;   d = xb;  base = id; }
  else if (id < 24576)  { s = ctx; d = cb;  base = id - 8192; }
  else if (id < 25600)  { s = wq;  d = wqb; base = id - 24576; }
  else if (id < 26624)  { s = wk;  d = wkb; base = id - 25600; }
  else if (id < 27648)  { s = wv;  d = wvb; base = id - 26624; }
  else                  { s = wo;  d = wob; base = id - 27648; }
  int i = base * 256 + threadIdx.x;
  float4 v = ((const float4*)s)[i];
  ushort4 o;
  o.x = __builtin_bit_cast(unsigned short, (bf16)v.x);
  o.y = __builtin_bit_cast(unsigned short, (bf16)v.y);
  o.z = __builtin_bit_cast(unsigned short, (bf16)v.z);
  o.w = __builtin_bit_cast(unsigned short, (bf16)v.w);
  ((ushort4*)d)[i] = o;
}

// ---------------- 8-phase 256x256 GEMM (T2+T3+T4): all four projections ----------
// BM=BN=256, BK=64, 8 waves (2Mx4N), LDS 128 KiB double-buffered.
// Per K-tile: 4 phases (C-quadrants, snake order) x 16 MFMA; staging 1 half-tile/phase
// into buf^1 via global_load_lds; counted vmcnt(2) + s_barrier once per K-tile.
// LDS swizzle: col8 ^= row&7 (pre-swizzled global source, XOR'd ds_read).
// [R8-verified structure — do not restructure; R9/R10/R11 variants all <= this]
template <int OUT_F32, int BIAS_ROW, int ROPE>
__global__ __launch_bounds__(512, 2) void gemm256(
    const bf16* __restrict__ A, const bf16* __restrict__ Bw,
    const float* __restrict__ bias, void* __restrict__ Cout,
    int N, int K, float oscale, const float* __restrict__ freqs) {
  __shared__ __align__(16) bf16 sA[2][16384];
  __shared__ __align__(16) bf16 sB[2][16384];

  int per = gridDim.x >> 3;
  int id = blockIdx.x;
  int swz = (id & 7) * per + (id >> 3);
  int NB = N >> 8;
  int mb = swz / NB, nb = swz % NB;

  int tid = threadIdx.x;
  int l = tid & 63, w = tid >> 6;
  int wm = w >> 2, wn = w & 3;
  int lr = l & 15, kg = l >> 4;

  int rw = w * 8 + (l >> 3);
  int cs = ((l & 7) ^ ((l >> 3) & 7)) * 8;
  const bf16* Ab = A + (size_t)(mb * 256 + rw) * K + cs;
  const bf16* Bb = Bw + (size_t)(nb * 256 + rw) * K + cs;

  auto stA = [&](int kt, int half, int buf) {
    const bf16* g = Ab + (size_t)(half * 128) * K + kt * 64;
    bf16* d = &sA[buf][half * 8192 + w * 512];
    async_cp16(g, d);
    async_cp16(g + (size_t)64 * K, d + 4096);
  };
  auto stB = [&](int kt, int half, int buf) {
    const bf16* g = Bb + (size_t)(half * 128) * K + kt * 64;
    bf16* d = &sB[buf][half * 8192 + w * 512];
    async_cp16(g, d);
    async_cp16(g + (size_t)64 * K, d + 4096);
  };

  f32x4 acc[8][4];
#pragma unroll
  for (int i = 0; i < 8; i++)
#pragma unroll
    for (int j = 0; j < 4; j++) acc[i][j] = f32x4{0.f, 0.f, 0.f, 0.f};

  int NT = K >> 6;

  stA(0, 0, 0); stA(0, 1, 0); stB(0, 0, 0); stB(0, 1, 0);
  asm volatile("s_waitcnt vmcnt(0)" ::: "memory");
  __builtin_amdgcn_s_barrier();

  int cur = 0;
  for (int t = 0; t < NT; ++t) {
    bool pf = (t + 1 < NT);
    if (pf) {
      stA(t + 1, 0, cur ^ 1);
      asm volatile("s_waitcnt vmcnt(2)" ::: "memory");
    } else {
      asm volatile("s_waitcnt vmcnt(0)" ::: "memory");
    }
    __builtin_amdgcn_s_barrier();

    const bf16* pA = sA[cur];
    const bf16* pB = sB[cur];
    bf16x8 afr[4][2], bq0[2][2], bq1[2][2];

    auto rdA = [&](int mh, int mf, int ks) {
      int rT = wm * 128 + mh * 64 + mf * 16 + lr;
      return *(const bf16x8*)&pA[rT * 64 + (((ks << 2) | kg) ^ (lr & 7)) * 8];
    };
    auto rdB = [&](int nfg, int ks) {
      int rT = wn * 64 + nfg * 16 + lr;
      return *(const bf16x8*)&pB[rT * 64 + (((ks << 2) | kg) ^ (lr & 7)) * 8];
    };

    // ---- phase 0: quad (mh0, nh0)
#pragma unroll
    for (int mf = 0; mf < 4; mf++) { afr[mf][0] = rdA(0, mf, 0); afr[mf][1] = rdA(0, mf, 1); }
#pragma unroll
    for (int nf = 0; nf < 2; nf++) { bq0[nf][0] = rdB(nf, 0); bq0[nf][1] = rdB(nf, 1); }
    __builtin_amdgcn_s_barrier();
    __builtin_amdgcn_s_setprio(1);
#pragma unroll
    for (int mf = 0; mf < 4; mf++)
#pragma unroll
      for (int nf = 0; nf < 2; nf++)
#pragma unroll
        for (int ks = 0; ks < 2; ks++)
          acc[mf][nf] = mfma16(afr[mf][ks], bq0[nf][ks], acc[mf][nf]);
    __builtin_amdgcn_s_setprio(0);
    __builtin_amdgcn_s_barrier();

    // ---- phase 1: quad (mh0, nh1); stage A-half1
#pragma unroll
    for (int nf = 0; nf < 2; nf++) { bq1[nf][0] = rdB(2 + nf, 0); bq1[nf][1] = rdB(2 + nf, 1); }
    if (pf) stA(t + 1, 1, cur ^ 1);
    __builtin_amdgcn_s_barrier();
    __builtin_amdgcn_s_setprio(1);
#pragma unroll
    for (int mf = 0; mf < 4; mf++)
#pragma unroll
      for (int nf = 0; nf < 2; nf++)
#pragma unroll
        for (int ks = 0; ks < 2; ks++)
          acc[mf][2 + nf] = mfma16(afr[mf][ks], bq1[nf][ks], acc[mf][2 + nf]);
    __builtin_amdgcn_s_setprio(0);
    __builtin_amdgcn_s_barrier();

    // ---- phase 2: quad (mh1, nh1); stage B-half0
#pragma unroll
    for (int mf = 0; mf < 4; mf++) { afr[mf][0] = rdA(1, mf, 0); afr[mf][1] = rdA(1, mf, 1); }
    if (pf) stB(t + 1, 0, cur ^ 1);
    __builtin_amdgcn_s_barrier();
    __builtin_amdgcn_s_setprio(1);
#pragma unroll
    for (int mf = 0; mf < 4; mf++)
#pragma unroll
      for (int nf = 0; nf < 2; nf++)
#pragma unroll
        for (int ks = 0; ks < 2; ks++)
          acc[4 + mf][2 + nf] = mfma16(afr[mf][ks], bq1[nf][ks], acc[4 + mf][2 + nf]);
    __builtin_amdgcn_s_setprio(0);
    __builtin_amdgcn_s_barrier();

    // ---- phase 3: quad (mh1, nh0); stage B-half1
    if (pf) stB(t + 1, 1, cur ^ 1);
    __builtin_amdgcn_s_barrier();
    __builtin_amdgcn_s_setprio(1);
#pragma unroll
    for (int mf = 0; mf < 4; mf++)
#pragma unroll
      for (int nf = 0; nf < 2; nf++)
#pragma unroll
        for (int ks = 0; ks < 2; ks++)
          acc[4 + mf][nf] = mfma16(afr[mf][ks], bq0[nf][ks], acc[4 + mf][nf]);
    __builtin_amdgcn_s_setprio(0);
    __builtin_amdgcn_s_barrier();

    cur ^= 1;
  }

  // ---- epilogue ----
  int row0 = mb * 256 + wm * 128 + (l >> 4) * 4;
  int col0 = nb * 256 + wn * 64 + lr;
  float sgn = (lr & 1) ? 1.f : -1.f;
#pragma unroll
  for (int fc = 0; fc < 4; fc++) {
    int c = col0 + fc * 16;
    float bi = BIAS_ROW ? 0.f : bias[c];
#pragma unroll
    for (int fr = 0; fr < 8; fr++) {
#pragma unroll
      for (int j = 0; j < 4; j++) {
        int r = row0 + fr * 16 + j;
        float v = acc[fr][fc][j] + (BIAS_ROW ? bias[r] : bi);
        if (ROPE) {
          float pv = __shfl_xor(v, 1, 64);
          float2 f = ((const float2*)freqs)[(size_t)(r & 2047) * 32 + ((c & 63) >> 1)];
          v = v * f.x + sgn * pv * f.y;
        }
        v *= oscale;
        if (OUT_F32)
          ((float*)Cout)[(size_t)r * N + c] = v;
        else
          ((bf16*)Cout)[(size_t)r * N + c] = (bf16)v;
      }
    }
  }
}

// ---------------- flash attention: swapped-QK^T 32x32, fixed-max softmax ----------------
__global__ __launch_bounds__(256, 4) void attn_fwd(
    const bf16* __restrict__ Q, const bf16* __restrict__ Kb,
    const bf16* __restrict__ VT, bf16* __restrict__ O) {
  __shared__ __align__(16) bf16 sK[2][4096];
  __shared__ __align__(16) bf16 sV[2][4096];

  int nblk = blockIdx.x;
  int bh = (nblk & 7) * 16 + (nblk >> 6);
  int qt = (nblk >> 3) & 7;
  int b = bh >> 4, h = bh & 15;

  int t = threadIdx.x, l = t & 63, w = t >> 6;
  int ln = l & 31, hi = l >> 5;

  int qg = qt * 128 + w * 32 + ln;
  const bf16* qp = Q + ((size_t)(b * 1024 + qg) * 16 + h) * 64 + hi * 8;
  bf16x8 qf[4];
#pragma unroll
  for (int ds = 0; ds < 4; ds++) qf[ds] = *(const bf16x8*)(qp + ds * 16);

  const bf16* kbase = Kb + ((size_t)b * 2048 * 16 + h) * 64;
  const bf16* vtbase = VT + (size_t)(h * 64) * 16384 + b * 2048;

  int krow = w * 8 + (l >> 3);
  int cg1 = ((l & 7) ^ (krow & 7) ^ ((krow >> 3) & 7)) * 8;
  int r2 = krow + 32;
  int cg2 = ((l & 7) ^ (r2 & 7) ^ ((r2 >> 3) & 7)) * 8;

  auto stageK = [&](int kv0, int nb) {
    async_cp16(kbase + (size_t)(kv0 + krow) * 1024 + cg1, &sK[nb][w * 512]);
    async_cp16(kbase + (size_t)(kv0 + r2) * 1024 + cg2, &sK[nb][2048 + w * 512]);
  };
  auto stageV = [&](int kv0, int nb) {
    async_cp16(vtbase + (size_t)krow * 16384 + kv0 + cg1, &sV[nb][w * 512]);
    async_cp16(vtbase + (size_t)r2 * 16384 + kv0 + cg2, &sV[nb][2048 + w * 512]);
  };

  f32x16 o0, o1, s0, s1, lacc, zero16;
#pragma unroll
  for (int i = 0; i < 16; i++) {
    o0[i] = 0.f; o1[i] = 0.f; lacc[i] = 0.f; zero16[i] = 0.f;
  }
  uint32_t one2 = 0x3f803f80u;
  u32x4 onesw; onesw[0] = one2; onesw[1] = one2; onesw[2] = one2; onesw[3] = one2;
  bf16x8 onesf = __builtin_bit_cast(bf16x8, onesw);

  stageK(0, 0);
  stageV(0, 0);
  __syncthreads();
  int cur = 0;

  int x0 = ((ln & 7) ^ (ln >> 3)) << 3;
  int x1 = x0 ^ (4 << 3);

  for (int tt = 0; tt < 32; tt++) {
    if (tt < 31) { stageK(tt * 64 + 64, cur ^ 1); stageV(tt * 64 + 64, cur ^ 1); }

    __builtin_amdgcn_s_setprio(1);
    {
      int boff = hi * 8;
      bf16x8 kf0 = *(const bf16x8*)&sK[cur][ln * 64 + (boff ^ x0)];
      bf16x8 kf1 = *(const bf16x8*)&sK[cur][(ln + 32) * 64 + (boff ^ x1)];
      s0 = mfma32(kf0, qf[0], zero16);
      s1 = mfma32(kf1, qf[0], zero16);
    }
#pragma unroll
    for (int ds = 1; ds < 4; ds++) {
      int boff = ds * 16 + hi * 8;
      bf16x8 kf0 = *(const bf16x8*)&sK[cur][ln * 64 + (boff ^ x0)];
      bf16x8 kf1 = *(const bf16x8*)&sK[cur][(ln + 32) * 64 + (boff ^ x1)];
      s0 = mfma32(kf0, qf[ds], s0);
      s1 = mfma32(kf1, qf[ds], s1);
    }
    __builtin_amdgcn_s_setprio(0);

#pragma unroll
    for (int i = 0; i < 16; i++) {
      s0[i] = __builtin_amdgcn_exp2f(s0[i]);
      s1[i] = __builtin_amdgcn_exp2f(s1[i]);
    }

    bf16x8 pa[4];
    auto mkfrags = [&](const f32x16& sv, int base) {
#pragma unroll
      for (int u = 0; u < 2; u++) {
        uint32_t w0a = cvtpk(sv[8 * u + 0], sv[8 * u + 1]);
        uint32_t w0b = cvtpk(sv[8 * u + 4], sv[8 * u + 5]);
        plswap(w0a, w0b);
        uint32_t w1a = cvtpk(sv[8 * u + 2], sv[8 * u + 3]);
        uint32_t w1b = cvtpk(sv[8 * u + 6], sv[8 * u + 7]);
        plswap(w1a, w1b);
        u32x4 tmp;
        tmp[0] = w0a; tmp[1] = w1a; tmp[2] = w0b; tmp[3] = w1b;
        pa[base + u] = __builtin_bit_cast(bf16x8, tmp);
      }
    };
    mkfrags(s0, 0);
    mkfrags(s1, 2);

    __builtin_amdgcn_s_setprio(1);
#pragma unroll
    for (int ks = 0; ks < 4; ks++) {
      int koff = ks * 16 + hi * 8;
      bf16x8 vf0 = *(const bf16x8*)&sV[cur][ln * 64 + (koff ^ x0)];
      bf16x8 vf1 = *(const bf16x8*)&sV[cur][(ln + 32) * 64 + (koff ^ x1)];
      o0 = mfma32(vf0, pa[ks], o0);
      o1 = mfma32(vf1, pa[ks], o1);
      lacc = mfma32(onesf, pa[ks], lacc);
    }
    __builtin_amdgcn_s_setprio(0);

    __syncthreads();
    cur ^= 1;
  }

  float inv = __builtin_amdgcn_rcpf(lacc[0]);
  bf16* obase = O + ((size_t)(b * 1024 + qt * 128 + w * 32 + ln) * 16 + h) * 64;
#pragma unroll
  for (int g = 0; g < 4; g++) {
    ushort4 p0, p1;
    p0.x = __builtin_bit_cast(unsigned short, (bf16)(o0[4 * g + 0] * inv));
    p0.y = __builtin_bit_cast(unsigned short, (bf16)(o0[4 * g + 1] * inv));
    p0.z = __builtin_bit_cast(unsigned short, (bf16)(o0[4 * g + 2] * inv));
    p0.w = __builtin_bit_cast(unsigned short, (bf16)(o0[4 * g + 3] * inv));
    p1.x = __builtin_bit_cast(unsigned short, (bf16)(o1[4 * g + 0] * inv));
    p1.y = __builtin_bit_cast(unsigned short, (bf16)(o1[4 * g + 1] * inv));
    p1.z = __builtin_bit_cast(unsigned short, (bf16)(o1[4 * g + 2] * inv));
    p1.w = __builtin_bit_cast(unsigned short, (bf16)(o1[4 * g + 3] * inv));
    *(ushort4*)&obase[8 * g + 4 * hi] = p0;
    *(ushort4*)&obase[32 + 8 * g + 4 * hi] = p1;
  }
}

// ---------------- launcher ----------------
extern "C" void kernel_launch(void* const* d_in, const int* in_sizes, int n_in,
                              void* d_out, int out_size, void* d_ws, size_t ws_size,
                              hipStream_t stream) {
  const float* x     = (const float*)d_in[0];
  const float* ctx   = (const float*)d_in[1];
  const float* freqs = (const float*)d_in[2];
  const float* wq    = (const float*)d_in[3];
  const float* bq    = (const float*)d_in[4];
  const float* wk    = (const float*)d_in[5];
  const float* bk    = (const float*)d_in[6];
  const float* wv    = (const float*)d_in[7];
  const float* bv    = (const float*)d_in[8];
  const float* wo    = (const float*)d_in[9];
  const float* bo    = (const float*)d_in[10];

  char* p = (char*)d_ws;
  bf16* xb  = (bf16*)p; p += (size_t)8192 * 1024 * 2;
  bf16* cb  = (bf16*)p; p += (size_t)16384 * 1024 * 2;
  bf16* wqb = (bf16*)p; p += (size_t)1024 * 1024 * 2;
  bf16* wkb = (bf16*)p; p += (size_t)1024 * 1024 * 2;
  bf16* wvb = (bf16*)p; p += (size_t)1024 * 1024 * 2;
  bf16* wob = (bf16*)p; p += (size_t)1024 * 1024 * 2;
  bf16* qb  = (bf16*)p; p += (size_t)8192 * 1024 * 2;
  bf16* kb  = (bf16*)p; p += (size_t)16384 * 1024 * 2;
  bf16* vt  = (bf16*)p; p += (size_t)16384 * 1024 * 2;  // V^T [1024][16384]
  bf16* ob  = xb;  // alias: x consumed before attention output is written

  const float K2 = 0.18033688011112042f;  // (1/sqrt(64)) * log2(e)

  convert_all<<<28672, 256, 0, stream>>>(x, ctx, wq, wk, wv, wo,
                                         xb, cb, wqb, wkb, wvb, wob);
  gemm256<0, 0, 0><<<128, 512, 0, stream>>>(xb, wqb, bq, qb, 1024, 1024, K2, nullptr);
  gemm256<0, 0, 1><<<256, 512, 0, stream>>>(cb, wkb, bk, kb, 1024, 1024, 1.0f, freqs);
  gemm256<0, 1, 0><<<256, 512, 0, stream>>>(wvb, cb, bv, vt, 16384, 1024, 1.0f, nullptr);
  attn_fwd<<<1024, 256, 0, stream>>>(qb, kb, vt, ob);
  gemm256<1, 0, 0><<<128, 512, 0, stream>>>(ob, wob, bo, d_out, 1024, 1024, 1.0f, nullptr);
}

// Round 13
// 276.181 us; speedup vs baseline: 1.1054x; 1.0878x over previous
//
#include <hip/hip_runtime.h>
#include <stdint.h>

typedef __bf16 bf16;
typedef bf16 bf16x8 __attribute__((ext_vector_type(8)));
typedef float f32x4 __attribute__((ext_vector_type(4)));
typedef float f32x16 __attribute__((ext_vector_type(16)));
typedef uint32_t u32x4 __attribute__((ext_vector_type(4)));

static __device__ __forceinline__ void async_cp16(const bf16* gsrc, bf16* ldst) {
  __builtin_amdgcn_global_load_lds(
      (const __attribute__((address_space(1))) uint32_t*)gsrc,
      (__attribute__((address_space(3))) uint32_t*)ldst, 16, 0, 0);
}

static __device__ __forceinline__ f32x16 mfma32(bf16x8 a, bf16x8 b, f32x16 c) {
  return __builtin_amdgcn_mfma_f32_32x32x16_bf16(a, b, c, 0, 0, 0);
}
static __device__ __forceinline__ f32x4 mfma16(bf16x8 a, bf16x8 b, f32x4 c) {
  return __builtin_amdgcn_mfma_f32_16x16x32_bf16(a, b, c, 0, 0, 0);
}

static __device__ __forceinline__ uint32_t cvtpk(float lo, float hi) {
  uint32_t r;
  asm("v_cvt_pk_bf16_f32 %0, %1, %2" : "=v"(r) : "v"(lo), "v"(hi));
  return r;
}
static __device__ __forceinline__ void plswap(uint32_t& a, uint32_t& b) {
  asm("v_permlane32_swap_b32 %0, %1" : "+v"(a), "+v"(b));
}

// ---------------- fp32 -> bf16 conversion (all tensors, one launch) ----------------
__global__ __launch_bounds__(256) void convert_all(
    const float* __restrict__ x, const float* __restrict__ ctx,
    const float* __restrict__ wq, const float* __restrict__ wk,
    const float* __restrict__ wv, const float* __restrict__ wo,
    bf16* __restrict__ xb, bf16* __restrict__ cb,
    bf16* __restrict__ wqb, bf16* __restrict__ wkb,
    bf16* __restrict__ wvb, bf16* __restrict__ wob) {
  int id = blockIdx.x;
  const float* s; bf16* d; int base;
  if (id < 8192)        { s = x;   d = xb;  base = id; }
  else if (id < 24576)  { s = ctx; d = cb;  base = id - 8192; }
  else if (id < 25600)  { s = wq;  d = wqb; base = id - 24576; }
  else if (id < 26624)  { s = wk;  d = wkb; base = id - 25600; }
  else if (id < 27648)  { s = wv;  d = wvb; base = id - 26624; }
  else                  { s = wo;  d = wob; base = id - 27648; }
  int i = base * 256 + threadIdx.x;
  float4 v = ((const float4*)s)[i];
  ushort4 o;
  o.x = __builtin_bit_cast(unsigned short, (bf16)v.x);
  o.y = __builtin_bit_cast(unsigned short, (bf16)v.y);
  o.z = __builtin_bit_cast(unsigned short, (bf16)v.z);
  o.w = __builtin_bit_cast(unsigned short, (bf16)v.w);
  ((ushort4*)d)[i] = o;
}

// ---------------- m97-structure GEMM (128x128): Q and O projections ----------
// 512 blocks -> 2 blocks/CU; beats 256^2 kernel on these M=8192 shapes (R12 lesson:
// work-per-CU, not per-kernel TFLOPS, dominates at small grids).
template <int OUT_F32, int BIAS_ROW = 0, int ROPE = 0>
__global__ __launch_bounds__(256) void gemm_bt(
    const bf16* __restrict__ A, const bf16* __restrict__ Bw,
    const float* __restrict__ bias, void* __restrict__ Cout,
    int M, int N, int K, float oscale, const float* __restrict__ freqs) {
  __shared__ __align__(16) bf16 sA[128 * 32];
  __shared__ __align__(16) bf16 sB[128 * 32];

  int per = gridDim.x >> 3;
  int id = blockIdx.x;
  int swz = (id & 7) * per + (id >> 3);
  int NB = N >> 7;
  int mb = swz / NB, nb = swz % NB;

  int t = threadIdx.x;
  int l = t & 63, w = t >> 6;
  int wr = (w >> 1) * 64, wc = (w & 1) * 64;
  int lr = l & 15, lk = (l >> 4) * 8;

  const bf16* Abase = A + (size_t)(mb * 128 + (t >> 2)) * K + (t & 3) * 8;
  const bf16* Bbase = Bw + (size_t)(nb * 128 + (t >> 2)) * K + (t & 3) * 8;
  bf16* ldsA = sA + w * 512;
  bf16* ldsB = sB + w * 512;

  f32x4 acc[4][4];
  for (int i = 0; i < 4; i++)
    for (int j = 0; j < 4; j++) acc[i][j] = f32x4{0.f, 0.f, 0.f, 0.f};

  for (int k0 = 0; k0 < K; k0 += 32) {
    async_cp16(Abase + k0, ldsA);
    async_cp16(Abase + k0 + (size_t)64 * K, ldsA + 2048);
    async_cp16(Bbase + k0, ldsB);
    async_cp16(Bbase + k0 + (size_t)64 * K, ldsB + 2048);
    __syncthreads();
    bf16x8 af[4], bfr[4];
    for (int mf = 0; mf < 4; mf++)
      af[mf] = *(const bf16x8*)&sA[(wr + mf * 16 + lr) * 32 + lk];
    for (int nf = 0; nf < 4; nf++)
      bfr[nf] = *(const bf16x8*)&sB[(wc + nf * 16 + lr) * 32 + lk];
    for (int mf = 0; mf < 4; mf++)
      for (int nf = 0; nf < 4; nf++)
        acc[mf][nf] = mfma16(af[mf], bfr[nf], acc[mf][nf]);
    __syncthreads();
  }

  int row0 = mb * 128 + wr + (l >> 4) * 4;
  int col0 = nb * 128 + wc + lr;
  float sgn = (lr & 1) ? 1.f : -1.f;
  for (int nf = 0; nf < 4; nf++) {
    int c = col0 + nf * 16;
    float bi = BIAS_ROW ? 0.f : bias[c];
    for (int mf = 0; mf < 4; mf++)
      for (int j = 0; j < 4; j++) {
        int r = row0 + mf * 16 + j;
        float v = acc[mf][nf][j] + (BIAS_ROW ? bias[r] : bi);
        if (ROPE) {
          float pv = __shfl_xor(v, 1, 64);
          float2 f = ((const float2*)freqs)[(size_t)(r & 2047) * 32 + ((c & 63) >> 1)];
          v = v * f.x + sgn * pv * f.y;
        }
        v *= oscale;
        if (OUT_F32)
          ((float*)Cout)[(size_t)r * N + c] = v;
        else
          ((bf16*)Cout)[(size_t)r * N + c] = (bf16)v;
      }
  }
}

// ---------------- 8-phase 256x256 GEMM (T2+T3+T4): K and V^T projections ----------
// [R8-verified structure — R9/R10/R11/R12 variants all <= this; do not restructure]
template <int OUT_F32, int BIAS_ROW, int ROPE>
__global__ __launch_bounds__(512, 2) void gemm256(
    const bf16* __restrict__ A, const bf16* __restrict__ Bw,
    const float* __restrict__ bias, void* __restrict__ Cout,
    int N, int K, float oscale, const float* __restrict__ freqs) {
  __shared__ __align__(16) bf16 sA[2][16384];
  __shared__ __align__(16) bf16 sB[2][16384];

  int per = gridDim.x >> 3;
  int id = blockIdx.x;
  int swz = (id & 7) * per + (id >> 3);
  int NB = N >> 8;
  int mb = swz / NB, nb = swz % NB;

  int tid = threadIdx.x;
  int l = tid & 63, w = tid >> 6;
  int wm = w >> 2, wn = w & 3;
  int lr = l & 15, kg = l >> 4;

  int rw = w * 8 + (l >> 3);
  int cs = ((l & 7) ^ ((l >> 3) & 7)) * 8;
  const bf16* Ab = A + (size_t)(mb * 256 + rw) * K + cs;
  const bf16* Bb = Bw + (size_t)(nb * 256 + rw) * K + cs;

  auto stA = [&](int kt, int half, int buf) {
    const bf16* g = Ab + (size_t)(half * 128) * K + kt * 64;
    bf16* d = &sA[buf][half * 8192 + w * 512];
    async_cp16(g, d);
    async_cp16(g + (size_t)64 * K, d + 4096);
  };
  auto stB = [&](int kt, int half, int buf) {
    const bf16* g = Bb + (size_t)(half * 128) * K + kt * 64;
    bf16* d = &sB[buf][half * 8192 + w * 512];
    async_cp16(g, d);
    async_cp16(g + (size_t)64 * K, d + 4096);
  };

  f32x4 acc[8][4];
#pragma unroll
  for (int i = 0; i < 8; i++)
#pragma unroll
    for (int j = 0; j < 4; j++) acc[i][j] = f32x4{0.f, 0.f, 0.f, 0.f};

  int NT = K >> 6;

  stA(0, 0, 0); stA(0, 1, 0); stB(0, 0, 0); stB(0, 1, 0);
  asm volatile("s_waitcnt vmcnt(0)" ::: "memory");
  __builtin_amdgcn_s_barrier();

  int cur = 0;
  for (int t = 0; t < NT; ++t) {
    bool pf = (t + 1 < NT);
    if (pf) {
      stA(t + 1, 0, cur ^ 1);
      asm volatile("s_waitcnt vmcnt(2)" ::: "memory");
    } else {
      asm volatile("s_waitcnt vmcnt(0)" ::: "memory");
    }
    __builtin_amdgcn_s_barrier();

    const bf16* pA = sA[cur];
    const bf16* pB = sB[cur];
    bf16x8 afr[4][2], bq0[2][2], bq1[2][2];

    auto rdA = [&](int mh, int mf, int ks) {
      int rT = wm * 128 + mh * 64 + mf * 16 + lr;
      return *(const bf16x8*)&pA[rT * 64 + (((ks << 2) | kg) ^ (lr & 7)) * 8];
    };
    auto rdB = [&](int nfg, int ks) {
      int rT = wn * 64 + nfg * 16 + lr;
      return *(const bf16x8*)&pB[rT * 64 + (((ks << 2) | kg) ^ (lr & 7)) * 8];
    };

    // ---- phase 0: quad (mh0, nh0)
#pragma unroll
    for (int mf = 0; mf < 4; mf++) { afr[mf][0] = rdA(0, mf, 0); afr[mf][1] = rdA(0, mf, 1); }
#pragma unroll
    for (int nf = 0; nf < 2; nf++) { bq0[nf][0] = rdB(nf, 0); bq0[nf][1] = rdB(nf, 1); }
    __builtin_amdgcn_s_barrier();
    __builtin_amdgcn_s_setprio(1);
#pragma unroll
    for (int mf = 0; mf < 4; mf++)
#pragma unroll
      for (int nf = 0; nf < 2; nf++)
#pragma unroll
        for (int ks = 0; ks < 2; ks++)
          acc[mf][nf] = mfma16(afr[mf][ks], bq0[nf][ks], acc[mf][nf]);
    __builtin_amdgcn_s_setprio(0);
    __builtin_amdgcn_s_barrier();

    // ---- phase 1: quad (mh0, nh1); stage A-half1
#pragma unroll
    for (int nf = 0; nf < 2; nf++) { bq1[nf][0] = rdB(2 + nf, 0); bq1[nf][1] = rdB(2 + nf, 1); }
    if (pf) stA(t + 1, 1, cur ^ 1);
    __builtin_amdgcn_s_barrier();
    __builtin_amdgcn_s_setprio(1);
#pragma unroll
    for (int mf = 0; mf < 4; mf++)
#pragma unroll
      for (int nf = 0; nf < 2; nf++)
#pragma unroll
        for (int ks = 0; ks < 2; ks++)
          acc[mf][2 + nf] = mfma16(afr[mf][ks], bq1[nf][ks], acc[mf][2 + nf]);
    __builtin_amdgcn_s_setprio(0);
    __builtin_amdgcn_s_barrier();

    // ---- phase 2: quad (mh1, nh1); stage B-half0
#pragma unroll
    for (int mf = 0; mf < 4; mf++) { afr[mf][0] = rdA(1, mf, 0); afr[mf][1] = rdA(1, mf, 1); }
    if (pf) stB(t + 1, 0, cur ^ 1);
    __builtin_amdgcn_s_barrier();
    __builtin_amdgcn_s_setprio(1);
#pragma unroll
    for (int mf = 0; mf < 4; mf++)
#pragma unroll
      for (int nf = 0; nf < 2; nf++)
#pragma unroll
        for (int ks = 0; ks < 2; ks++)
          acc[4 + mf][2 + nf] = mfma16(afr[mf][ks], bq1[nf][ks], acc[4 + mf][2 + nf]);
    __builtin_amdgcn_s_setprio(0);
    __builtin_amdgcn_s_barrier();

    // ---- phase 3: quad (mh1, nh0); stage B-half1
    if (pf) stB(t + 1, 1, cur ^ 1);
    __builtin_amdgcn_s_barrier();
    __builtin_amdgcn_s_setprio(1);
#pragma unroll
    for (int mf = 0; mf < 4; mf++)
#pragma unroll
      for (int nf = 0; nf < 2; nf++)
#pragma unroll
        for (int ks = 0; ks < 2; ks++)
          acc[4 + mf][nf] = mfma16(afr[mf][ks], bq0[nf][ks], acc[4 + mf][nf]);
    __builtin_amdgcn_s_setprio(0);
    __builtin_amdgcn_s_barrier();

    cur ^= 1;
  }

  // ---- epilogue ----
  int row0 = mb * 256 + wm * 128 + (l >> 4) * 4;
  int col0 = nb * 256 + wn * 64 + lr;
  float sgn = (lr & 1) ? 1.f : -1.f;
#pragma unroll
  for (int fc = 0; fc < 4; fc++) {
    int c = col0 + fc * 16;
    float bi = BIAS_ROW ? 0.f : bias[c];
#pragma unroll
    for (int fr = 0; fr < 8; fr++) {
#pragma unroll
      for (int j = 0; j < 4; j++) {
        int r = row0 + fr * 16 + j;
        float v = acc[fr][fc][j] + (BIAS_ROW ? bias[r] : bi);
        if (ROPE) {
          float pv = __shfl_xor(v, 1, 64);
          float2 f = ((const float2*)freqs)[(size_t)(r & 2047) * 32 + ((c & 63) >> 1)];
          v = v * f.x + sgn * pv * f.y;
        }
        v *= oscale;
        if (OUT_F32)
          ((float*)Cout)[(size_t)r * N + c] = v;
        else
          ((bf16*)Cout)[(size_t)r * N + c] = (bf16)v;
      }
    }
  }
}

// ---------------- flash attention: swapped-QK^T 32x32, fixed-max softmax ----------------
__global__ __launch_bounds__(256, 4) void attn_fwd(
    const bf16* __restrict__ Q, const bf16* __restrict__ Kb,
    const bf16* __restrict__ VT, bf16* __restrict__ O) {
  __shared__ __align__(16) bf16 sK[2][4096];
  __shared__ __align__(16) bf16 sV[2][4096];

  int nblk = blockIdx.x;
  int bh = (nblk & 7) * 16 + (nblk >> 6);
  int qt = (nblk >> 3) & 7;
  int b = bh >> 4, h = bh & 15;

  int t = threadIdx.x, l = t & 63, w = t >> 6;
  int ln = l & 31, hi = l >> 5;

  int qg = qt * 128 + w * 32 + ln;
  const bf16* qp = Q + ((size_t)(b * 1024 + qg) * 16 + h) * 64 + hi * 8;
  bf16x8 qf[4];
#pragma unroll
  for (int ds = 0; ds < 4; ds++) qf[ds] = *(const bf16x8*)(qp + ds * 16);

  const bf16* kbase = Kb + ((size_t)b * 2048 * 16 + h) * 64;
  const bf16* vtbase = VT + (size_t)(h * 64) * 16384 + b * 2048;

  int krow = w * 8 + (l >> 3);
  int cg1 = ((l & 7) ^ (krow & 7) ^ ((krow >> 3) & 7)) * 8;
  int r2 = krow + 32;
  int cg2 = ((l & 7) ^ (r2 & 7) ^ ((r2 >> 3) & 7)) * 8;

  auto stageK = [&](int kv0, int nb) {
    async_cp16(kbase + (size_t)(kv0 + krow) * 1024 + cg1, &sK[nb][w * 512]);
    async_cp16(kbase + (size_t)(kv0 + r2) * 1024 + cg2, &sK[nb][2048 + w * 512]);
  };
  auto stageV = [&](int kv0, int nb) {
    async_cp16(vtbase + (size_t)krow * 16384 + kv0 + cg1, &sV[nb][w * 512]);
    async_cp16(vtbase + (size_t)r2 * 16384 + kv0 + cg2, &sV[nb][2048 + w * 512]);
  };

  f32x16 o0, o1, s0, s1, lacc, zero16;
#pragma unroll
  for (int i = 0; i < 16; i++) {
    o0[i] = 0.f; o1[i] = 0.f; lacc[i] = 0.f; zero16[i] = 0.f;
  }
  uint32_t one2 = 0x3f803f80u;
  u32x4 onesw; onesw[0] = one2; onesw[1] = one2; onesw[2] = one2; onesw[3] = one2;
  bf16x8 onesf = __builtin_bit_cast(bf16x8, onesw);

  stageK(0, 0);
  stageV(0, 0);
  __syncthreads();
  int cur = 0;

  int x0 = ((ln & 7) ^ (ln >> 3)) << 3;
  int x1 = x0 ^ (4 << 3);

  for (int tt = 0; tt < 32; tt++) {
    if (tt < 31) { stageK(tt * 64 + 64, cur ^ 1); stageV(tt * 64 + 64, cur ^ 1); }

    __builtin_amdgcn_s_setprio(1);
    {
      int boff = hi * 8;
      bf16x8 kf0 = *(const bf16x8*)&sK[cur][ln * 64 + (boff ^ x0)];
      bf16x8 kf1 = *(const bf16x8*)&sK[cur][(ln + 32) * 64 + (boff ^ x1)];
      s0 = mfma32(kf0, qf[0], zero16);
      s1 = mfma32(kf1, qf[0], zero16);
    }
#pragma unroll
    for (int ds = 1; ds < 4; ds++) {
      int boff = ds * 16 + hi * 8;
      bf16x8 kf0 = *(const bf16x8*)&sK[cur][ln * 64 + (boff ^ x0)];
      bf16x8 kf1 = *(const bf16x8*)&sK[cur][(ln + 32) * 64 + (boff ^ x1)];
      s0 = mfma32(kf0, qf[ds], s0);
      s1 = mfma32(kf1, qf[ds], s1);
    }
    __builtin_amdgcn_s_setprio(0);

#pragma unroll
    for (int i = 0; i < 16; i++) {
      s0[i] = __builtin_amdgcn_exp2f(s0[i]);
      s1[i] = __builtin_amdgcn_exp2f(s1[i]);
    }

    bf16x8 pa[4];
    auto mkfrags = [&](const f32x16& sv, int base) {
#pragma unroll
      for (int u = 0; u < 2; u++) {
        uint32_t w0a = cvtpk(sv[8 * u + 0], sv[8 * u + 1]);
        uint32_t w0b = cvtpk(sv[8 * u + 4], sv[8 * u + 5]);
        plswap(w0a, w0b);
        uint32_t w1a = cvtpk(sv[8 * u + 2], sv[8 * u + 3]);
        uint32_t w1b = cvtpk(sv[8 * u + 6], sv[8 * u + 7]);
        plswap(w1a, w1b);
        u32x4 tmp;
        tmp[0] = w0a; tmp[1] = w1a; tmp[2] = w0b; tmp[3] = w1b;
        pa[base + u] = __builtin_bit_cast(bf16x8, tmp);
      }
    };
    mkfrags(s0, 0);
    mkfrags(s1, 2);

    __builtin_amdgcn_s_setprio(1);
#pragma unroll
    for (int ks = 0; ks < 4; ks++) {
      int koff = ks * 16 + hi * 8;
      bf16x8 vf0 = *(const bf16x8*)&sV[cur][ln * 64 + (koff ^ x0)];
      bf16x8 vf1 = *(const bf16x8*)&sV[cur][(ln + 32) * 64 + (koff ^ x1)];
      o0 = mfma32(vf0, pa[ks], o0);
      o1 = mfma32(vf1, pa[ks], o1);
      lacc = mfma32(onesf, pa[ks], lacc);
    }
    __builtin_amdgcn_s_setprio(0);

    __syncthreads();
    cur ^= 1;
  }

  float inv = __builtin_amdgcn_rcpf(lacc[0]);
  bf16* obase = O + ((size_t)(b * 1024 + qt * 128 + w * 32 + ln) * 16 + h) * 64;
#pragma unroll
  for (int g = 0; g < 4; g++) {
    ushort4 p0, p1;
    p0.x = __builtin_bit_cast(unsigned short, (bf16)(o0[4 * g + 0] * inv));
    p0.y = __builtin_bit_cast(unsigned short, (bf16)(o0[4 * g + 1] * inv));
    p0.z = __builtin_bit_cast(unsigned short, (bf16)(o0[4 * g + 2] * inv));
    p0.w = __builtin_bit_cast(unsigned short, (bf16)(o0[4 * g + 3] * inv));
    p1.x = __builtin_bit_cast(unsigned short, (bf16)(o1[4 * g + 0] * inv));
    p1.y = __builtin_bit_cast(unsigned short, (bf16)(o1[4 * g + 1] * inv));
    p1.z = __builtin_bit_cast(unsigned short, (bf16)(o1[4 * g + 2] * inv));
    p1.w = __builtin_bit_cast(unsigned short, (bf16)(o1[4 * g + 3] * inv));
    *(ushort4*)&obase[8 * g + 4 * hi] = p0;
    *(ushort4*)&obase[32 + 8 * g + 4 * hi] = p1;
  }
}

// ---------------- launcher ----------------
extern "C" void kernel_launch(void* const* d_in, const int* in_sizes, int n_in,
                              void* d_out, int out_size, void* d_ws, size_t ws_size,
                              hipStream_t stream) {
  const float* x     = (const float*)d_in[0];
  const float* ctx   = (const float*)d_in[1];
  const float* freqs = (const float*)d_in[2];
  const float* wq    = (const float*)d_in[3];
  const float* bq    = (const float*)d_in[4];
  const float* wk    = (const float*)d_in[5];
  const float* bk    = (const float*)d_in[6];
  const float* wv    = (const float*)d_in[7];
  const float* bv    = (const float*)d_in[8];
  const float* wo    = (const float*)d_in[9];
  const float* bo    = (const float*)d_in[10];

  char* p = (char*)d_ws;
  bf16* xb  = (bf16*)p; p += (size_t)8192 * 1024 * 2;
  bf16* cb  = (bf16*)p; p += (size_t)16384 * 1024 * 2;
  bf16* wqb = (bf16*)p; p += (size_t)1024 * 1024 * 2;
  bf16* wkb = (bf16*)p; p += (size_t)1024 * 1024 * 2;
  bf16* wvb = (bf16*)p; p += (size_t)1024 * 1024 * 2;
  bf16* wob = (bf16*)p; p += (size_t)1024 * 1024 * 2;
  bf16* qb  = (bf16*)p; p += (size_t)8192 * 1024 * 2;
  bf16* kb  = (bf16*)p; p += (size_t)16384 * 1024 * 2;
  bf16* vt  = (bf16*)p; p += (size_t)16384 * 1024 * 2;  // V^T [1024][16384]
  bf16* ob  = xb;  // alias: x consumed before attention output is written

  const float K2 = 0.18033688011112042f;  // (1/sqrt(64)) * log2(e)

  convert_all<<<28672, 256, 0, stream>>>(x, ctx, wq, wk, wv, wo,
                                         xb, cb, wqb, wkb, wvb, wob);
  gemm_bt<0><<<512, 256, 0, stream>>>(xb, wqb, bq, qb, 8192, 1024, 1024, K2, nullptr);
  gemm256<0, 0, 1><<<256, 512, 0, stream>>>(cb, wkb, bk, kb, 1024, 1024, 1.0f, freqs);
  gemm256<0, 1, 0><<<256, 512, 0, stream>>>(wvb, cb, bv, vt, 16384, 1024, 1.0f, nullptr);
  attn_fwd<<<1024, 256, 0, stream>>>(qb, kb, vt, ob);
  gemm_bt<1><<<512, 256, 0, stream>>>(ob, wob, bo, d_out, 8192, 1024, 1024, 1.0f, nullptr);
}